// Round 5
// baseline (309.305 us; speedup 1.0000x reference)
//
#include <hip/hip_runtime.h>
#include <math.h>

// Problem constants
#define NN 8
#define C_TOTAL 448
#define CC 100
#define HH 56
#define WW 56
#define HW (HH*WW)          // 3136
#define NPIX4 (HW/4)        // 784 quads (float4 pixel groups)
#define OH 224
#define OW 224
#define NT4 13              // ceil(784/64) quad tiles
#define NG 25               // row groups of 4: group k = rows 4k..4k+3
#define KSPLIT 12           // groups k<KSPLIT get their d-range split in 2 blocks
#define NKIND (2*KSPLIT + (NG - KSPLIT))   // 37 block kinds per tile
#define QREP 3              // INSTRUMENTATION: repeat qform work in-dispatch (idempotent)

typedef __attribute__((ext_vector_type(4))) _Float16 half4;
typedef __attribute__((ext_vector_type(8))) _Float16 half8;
typedef __attribute__((ext_vector_type(4))) float    f32x4;

__device__ __forceinline__ f32x4 cvtlo(const half8 h) {
    return __builtin_convertvector(__builtin_shufflevector(h, h, 0, 1, 2, 3), f32x4);
}
__device__ __forceinline__ f32x4 cvthi(const half8 h) {
    return __builtin_convertvector(__builtin_shufflevector(h, h, 4, 5, 6, 7), f32x4);
}
__device__ __forceinline__ f32x4 fmav(const f32x4 a, const f32x4 b, const f32x4 c) {
    f32x4 r;
    r.x = fmaf(a.x, b.x, c.x);
    r.y = fmaf(a.y, b.y, c.y);
    r.z = fmaf(a.z, b.z, c.z);
    r.w = fmaf(a.w, b.w, c.w);
    return r;
}

// ---------------------------------------------------------------------------
// Kernel 0: x -> fp16, TRANSPOSED layout xbuf[c][quad][n] (half4 elements).
// ---------------------------------------------------------------------------
__global__ __launch_bounds__(256) void prep_x_kernel(
    const float* __restrict__ fmaps, const int* __restrict__ sel,
    const float* __restrict__ mean, half4* __restrict__ xbuf)
{
    const int idx = blockIdx.x * 256 + threadIdx.x;
    if (idx >= CC * NPIX4) return;
    const int quad = idx % NPIX4;
    const int c    = idx / NPIX4;

    const float4* f4 = (const float4*)fmaps;
    const float4  m  = ((const float4*)mean)[(size_t)c * NPIX4 + quad];
    const int     sc = sel[c];

    half4 hv[NN];
#pragma unroll
    for (int n = 0; n < NN; ++n) {
        const float4 f = f4[((size_t)n * C_TOTAL + sc) * NPIX4 + quad];
        half4 h;
        h.x = (_Float16)(f.x - m.x);
        h.y = (_Float16)(f.y - m.y);
        h.z = (_Float16)(f.z - m.z);
        h.w = (_Float16)(f.w - m.w);
        hv[n] = h;
    }
    half4* dst = xbuf + ((size_t)c * NPIX4 + quad) * NN;   // 64 B contiguous
#pragma unroll
    for (int n = 0; n < NN; ++n) dst[n] = hv[n];
}

// ---------------------------------------------------------------------------
// Kernel 1: R4 structure, two changes:
//  (a) atomics -> per-kind qpart STORES (A/B test of atomic contention;
//      makes the kernel idempotent),
//  (b) QREP=3 identical in-dispatch repetitions so this dispatch ranks in
//      the top-5 counter table next round (dur/3 = qform time, plus
//      VALUBusy / OccupancyPercent / FETCH_SIZE / VGPR_Count).
//      #pragma unroll 1 + asm memory clobber prevent cross-rep CSE.
// ---------------------------------------------------------------------------
__global__ __launch_bounds__(512, 4) void qform_kernel(
    const half4* __restrict__ xbuf, const float* __restrict__ cov,
    float* __restrict__ qpart)
{
    __shared__ f32x4 lred[8 * 4 * 64];   // [wave][img-slot][lane] = 32 KB

    const int tile = blockIdx.x % NT4;
    const int kind = blockIdx.x / NT4;
    int k, h, split;
    if (kind < 2 * KSPLIT) { k = kind >> 1; h = kind & 1; split = 1; }
    else                   { k = kind - KSPLIT; h = 0; split = 0; }
    const int a   = 4 * k;
    const int L   = CC - a;
    const int mid = a + ((L + 1) >> 1);

    const int w    = threadIdx.x >> 6;   // wave id 0..7
    const int dph  = w & 1;              // d parity phase
    const int rh   = (w >> 1) & 1;       // row half: rows a+2rh, a+2rh+1
    const int imgh = w >> 2;             // image half (0: n=0..3, 1: n=4..7)
    const int lane = threadIdx.x & 63;
    const int qraw = tile * 64 + lane;
    const bool valid = qraw < NPIX4;
    const int quad = valid ? qraw : (NPIX4 - 1);   // clamp, no early return

    const int r0 = a + 2 * rh;
    const int r1 = r0 + 1;

    const f32x4* c4  = (const f32x4*)cov;
    const half8* xb8 = (const half8*)xbuf;

#pragma unroll 1
    for (int rep = 0; rep < QREP; ++rep) {

    f32x4 acc[2][4];                     // [row in half][img]
#pragma unroll
    for (int i = 0; i < 2; ++i)
#pragma unroll
        for (int j = 0; j < 4; ++j) acc[i][j] = (f32x4){0.f, 0.f, 0.f, 0.f};

    int lo, hi;
    if (split && h == 1) {
        lo = mid + (((mid ^ (a + dph)) & 1));
        hi = CC;
    } else {
        hi = split ? mid : CC;
        const int d0 = r0 + dph;
        {
            const half8* xp = xb8 + ((size_t)d0 * NPIX4 + quad) * 4 + imgh * 2;
            const half8 hA = xp[0];
            const half8 hB = xp[1];
            f32x4 xv[4];
            xv[0] = cvtlo(hA); xv[1] = cvthi(hA);
            xv[2] = cvtlo(hB); xv[3] = cvthi(hB);
            f32x4 cv0 = __builtin_nontemporal_load(&c4[((size_t)r0 * CC + d0) * NPIX4 + quad]);
            if (dph == 0) {
                cv0 *= 0.5f;             // d0 == r0: diagonal of r0
#pragma unroll
                for (int j = 0; j < 4; ++j) acc[0][j] = fmav(xv[j], cv0, acc[0][j]);
            } else {
                // d0 == r1: r0 full, r1 diagonal
#pragma unroll
                for (int j = 0; j < 4; ++j) acc[0][j] = fmav(xv[j], cv0, acc[0][j]);
                f32x4 cv1 = __builtin_nontemporal_load(&c4[((size_t)r1 * CC + d0) * NPIX4 + quad]);
                cv1 *= 0.5f;
#pragma unroll
                for (int j = 0; j < 4; ++j) acc[1][j] = fmav(xv[j], cv1, acc[1][j]);
            }
        }
        lo = r0 + dph + 2;
    }

    // ---- main loop, unrolled x2 (8 loads in flight), both rows full ----
    int d = lo;
    for (; d + 2 < hi; d += 4) {
        const half8* xp0 = xb8 + ((size_t)d * NPIX4 + quad) * 4 + imgh * 2;
        const half8* xp1 = xb8 + ((size_t)(d + 2) * NPIX4 + quad) * 4 + imgh * 2;
        const half8 a0 = xp0[0];
        const half8 b0 = xp0[1];
        const half8 a1 = xp1[0];
        const half8 b1 = xp1[1];
        const size_t cb0 = ((size_t)r0 * CC + d) * NPIX4 + quad;
        const size_t cb1 = ((size_t)r1 * CC + d) * NPIX4 + quad;
        const f32x4 c00 = __builtin_nontemporal_load(&c4[cb0]);
        const f32x4 c10 = __builtin_nontemporal_load(&c4[cb1]);
        const f32x4 c01 = __builtin_nontemporal_load(&c4[cb0 + 2 * NPIX4]);
        const f32x4 c11 = __builtin_nontemporal_load(&c4[cb1 + 2 * NPIX4]);

        {
            f32x4 xv[4];
            xv[0] = cvtlo(a0); xv[1] = cvthi(a0);
            xv[2] = cvtlo(b0); xv[3] = cvthi(b0);
#pragma unroll
            for (int j = 0; j < 4; ++j) acc[0][j] = fmav(xv[j], c00, acc[0][j]);
#pragma unroll
            for (int j = 0; j < 4; ++j) acc[1][j] = fmav(xv[j], c10, acc[1][j]);
        }
        {
            f32x4 xv[4];
            xv[0] = cvtlo(a1); xv[1] = cvthi(a1);
            xv[2] = cvtlo(b1); xv[3] = cvthi(b1);
#pragma unroll
            for (int j = 0; j < 4; ++j) acc[0][j] = fmav(xv[j], c01, acc[0][j]);
#pragma unroll
            for (int j = 0; j < 4; ++j) acc[1][j] = fmav(xv[j], c11, acc[1][j]);
        }
    }
    if (d < hi) {                        // tail column
        const half8* xp = xb8 + ((size_t)d * NPIX4 + quad) * 4 + imgh * 2;
        const half8 hA = xp[0];
        const half8 hB = xp[1];
        const f32x4 c0 = __builtin_nontemporal_load(&c4[((size_t)r0 * CC + d) * NPIX4 + quad]);
        const f32x4 c1 = __builtin_nontemporal_load(&c4[((size_t)r1 * CC + d) * NPIX4 + quad]);
        f32x4 xv[4];
        xv[0] = cvtlo(hA); xv[1] = cvthi(hA);
        xv[2] = cvtlo(hB); xv[3] = cvthi(hB);
#pragma unroll
        for (int j = 0; j < 4; ++j) acc[0][j] = fmav(xv[j], c0, acc[0][j]);
#pragma unroll
        for (int j = 0; j < 4; ++j) acc[1][j] = fmav(xv[j], c1, acc[1][j]);
    }

    // ---- fold: part[j] = 2*(x_r0[j]*acc0[j] + x_r1[j]*acc1[j]); LDS dump ----
    {
        const half8* x0p = xb8 + ((size_t)r0 * NPIX4 + quad) * 4 + imgh * 2;
        const half8* x1p = xb8 + ((size_t)r1 * NPIX4 + quad) * 4 + imgh * 2;
        const half8 xa0 = x0p[0], xb0 = x0p[1];
        const half8 xa1 = x1p[0], xb1 = x1p[1];
        f32x4 part[4];
        part[0] = cvtlo(xa0) * acc[0][0];
        part[1] = cvthi(xa0) * acc[0][1];
        part[2] = cvtlo(xb0) * acc[0][2];
        part[3] = cvthi(xb0) * acc[0][3];
        part[0] = fmav(cvtlo(xa1), acc[1][0], part[0]);
        part[1] = fmav(cvthi(xa1), acc[1][1], part[1]);
        part[2] = fmav(cvtlo(xb1), acc[1][2], part[2]);
        part[3] = fmav(cvthi(xb1), acc[1][3], part[3]);
#pragma unroll
        for (int j = 0; j < 4; ++j) {
            part[j] = part[j] + part[j];             // x2 (symmetry)
            lred[(w * 4 + j) * 64 + lane] = part[j];
        }
    }
    __syncthreads();

    // ---- final: wave w stores image w's block-partial to qpart[kind] ----
    {
        const int im = w;                // 0..7
        const int sh = (im >> 2) * 4;    // source imgh base wave
        const int sl = im & 3;           // slot within image half
        f32x4 s = (f32x4){0.f, 0.f, 0.f, 0.f};
#pragma unroll
        for (int sw = 0; sw < 4; ++sw) { // (rh, dph) combos
            s = s + lred[((sh + sw) * 4 + sl) * 64 + lane];
        }
        if (valid) {
            ((f32x4*)qpart)[((size_t)kind * NN + im) * NPIX4 + qraw] = s;
        }
    }
    __syncthreads();                     // protect lred across reps
    asm volatile("" ::: "memory");       // forbid cross-rep CSE of loads/stores

    } // rep
}

// ---------------------------------------------------------------------------
// Kernel 2: reduce the 37 kind-partials, sqrt -> smap (N, HW)
// ---------------------------------------------------------------------------
__global__ __launch_bounds__(256) void reduce_kernel(
    const float* __restrict__ qpart, float* __restrict__ smap)
{
    const int idx = blockIdx.x * 256 + threadIdx.x;   // over NN*NPIX4
    if (idx >= NN * NPIX4) return;
    const int p4 = idx % NPIX4;
    const int n  = idx / NPIX4;

    const f32x4* qp = (const f32x4*)qpart;
    f32x4 acc = (f32x4){0.f, 0.f, 0.f, 0.f};
#pragma unroll
    for (int kk = 0; kk < NKIND; ++kk) {
        acc = acc + qp[((size_t)kk * NN + n) * NPIX4 + p4];
    }
    f32x4 o;
    o.x = sqrtf(fmaxf(acc.x, 0.f));
    o.y = sqrtf(fmaxf(acc.y, 0.f));
    o.z = sqrtf(fmaxf(acc.z, 0.f));
    o.w = sqrtf(fmaxf(acc.w, 0.f));
    ((f32x4*)smap)[(size_t)n * NPIX4 + p4] = o;
}

// ---------------------------------------------------------------------------
// Kernel 3: bilinear x4 upsample (half-pixel, edge clamp) + normalize
// (smap is already sqrt'd)
// ---------------------------------------------------------------------------
__global__ __launch_bounds__(256) void upsample_kernel(
    const float* __restrict__ smap,
    const float* __restrict__ minp, const float* __restrict__ maxp,
    float* __restrict__ out)
{
    const int idx = blockIdx.x * 256 + threadIdx.x;
    const int total = NN * OH * OW;
    if (idx >= total) return;

    const int ox = idx % OW;
    const int oy = (idx / OW) % OH;
    const int n  = idx / (OW * OH);

    const float fy = oy * 0.25f - 0.375f;
    const float fx = ox * 0.25f - 0.375f;

    int y0 = (int)floorf(fy);
    int x0 = (int)floorf(fx);
    const float wy = fy - (float)y0;
    const float wx = fx - (float)x0;
    int y1 = min(y0 + 1, HH - 1); y0 = max(y0, 0);
    int x1 = min(x0 + 1, WW - 1); x0 = max(x0, 0);

    const float* s = smap + (size_t)n * HW;
    const float v00 = s[y0 * WW + x0];
    const float v01 = s[y0 * WW + x1];
    const float v10 = s[y1 * WW + x0];
    const float v11 = s[y1 * WW + x1];

    const float v = (1.0f - wy) * ((1.0f - wx) * v00 + wx * v01)
                  +          wy * ((1.0f - wx) * v10 + wx * v11);

    const float mn = *minp;
    const float mx = *maxp;
    out[idx] = (v - mn) / (mx - mn);
}

// ---------------------------------------------------------------------------
extern "C" void kernel_launch(void* const* d_in, const int* in_sizes, int n_in,
                              void* d_out, int out_size, void* d_ws, size_t ws_size,
                              hipStream_t stream)
{
    const float* fmaps = (const float*)d_in[0];
    const int*   sel   = (const int*)  d_in[1];
    const float* mean  = (const float*)d_in[2];
    const float* cov   = (const float*)d_in[3];
    const float* minp  = (const float*)d_in[4];
    const float* maxp  = (const float*)d_in[5];
    float* out = (float*)d_out;

    half4* xbuf  = (half4*)d_ws;                                      // 5.02 MB
    float* qpart = (float*)((char*)d_ws + (size_t)CC*NPIX4*NN*8);     // NKIND*NN*HW f32 = 3.71 MB
    float* smap  = qpart + (size_t)NKIND * NN * HW;                   // NN*HW f32 = 0.1 MB

    {
        const int total = CC * NPIX4;
        prep_x_kernel<<<(total + 255) / 256, 256, 0, stream>>>(fmaps, sel, mean, xbuf);
    }
    qform_kernel<<<NKIND * NT4, 512, 0, stream>>>(xbuf, cov, qpart);
    {
        const int total = NN * NPIX4;
        reduce_kernel<<<(total + 255) / 256, 256, 0, stream>>>(qpart, smap);
    }
    {
        const int total = NN * OH * OW;
        upsample_kernel<<<(total + 255) / 256, 256, 0, stream>>>(smap, minp, maxp, out);
    }
}

// Round 6
// 224.130 us; speedup vs baseline: 1.3800x; 1.3800x over previous
//
#include <hip/hip_runtime.h>
#include <math.h>

// Problem constants
#define NN 8
#define C_TOTAL 448
#define CC 100
#define HH 56
#define WW 56
#define HW (HH*WW)          // 3136
#define NPIX4 (HW/4)        // 784 quads (float4 pixel groups)
#define OH 224
#define OW 224
#define NT4 13              // ceil(784/64) quad tiles
#define NG 25               // row groups of 4: group k = rows 4k..4k+3
#define CH 16               // d-chunk width (even!)
#define NKIND 91            // sum_k ceil((100-4k)/16) ; 91 = 7*13
#define KG 7                // reduce kind-groups (13 kinds each)

typedef __attribute__((ext_vector_type(4))) _Float16 half4;
typedef __attribute__((ext_vector_type(8))) _Float16 half8;
typedef __attribute__((ext_vector_type(4))) float    f32x4;

__device__ __forceinline__ f32x4 cvtlo(const half8 h) {
    return __builtin_convertvector(__builtin_shufflevector(h, h, 0, 1, 2, 3), f32x4);
}
__device__ __forceinline__ f32x4 cvthi(const half8 h) {
    return __builtin_convertvector(__builtin_shufflevector(h, h, 4, 5, 6, 7), f32x4);
}
__device__ __forceinline__ f32x4 fmav(const f32x4 a, const f32x4 b, const f32x4 c) {
    f32x4 r;
    r.x = fmaf(a.x, b.x, c.x);
    r.y = fmaf(a.y, b.y, c.y);
    r.z = fmaf(a.z, b.z, c.z);
    r.w = fmaf(a.w, b.w, c.w);
    return r;
}

// ---------------------------------------------------------------------------
// Kernel 0: x -> fp16, TRANSPOSED layout xbuf[c][quad][n] (half4 elements).
// Also zeroes the smap accumulator (first NN*NPIX4 threads).
// ---------------------------------------------------------------------------
__global__ __launch_bounds__(256) void prep_x_kernel(
    const float* __restrict__ fmaps, const int* __restrict__ sel,
    const float* __restrict__ mean, half4* __restrict__ xbuf,
    float* __restrict__ smap)
{
    const int idx = blockIdx.x * 256 + threadIdx.x;
    if (idx < NN * NPIX4) {
        ((float4*)smap)[idx] = make_float4(0.f, 0.f, 0.f, 0.f);
    }
    if (idx >= CC * NPIX4) return;
    const int quad = idx % NPIX4;
    const int c    = idx / NPIX4;

    const float4* f4 = (const float4*)fmaps;
    const float4  m  = ((const float4*)mean)[(size_t)c * NPIX4 + quad];
    const int     sc = sel[c];

    half4 hv[NN];
#pragma unroll
    for (int n = 0; n < NN; ++n) {
        const float4 f = f4[((size_t)n * C_TOTAL + sc) * NPIX4 + quad];
        half4 h;
        h.x = (_Float16)(f.x - m.x);
        h.y = (_Float16)(f.y - m.y);
        h.z = (_Float16)(f.z - m.z);
        h.w = (_Float16)(f.w - m.w);
        hv[n] = h;
    }
    half4* dst = xbuf + ((size_t)c * NPIX4 + quad) * NN;   // 64 B contiguous
#pragma unroll
    for (int n = 0; n < NN; ++n) dst[n] = hv[n];
}

// ---------------------------------------------------------------------------
// Kernel 1: R4 structure + d-CHUNKING for occupancy (R5 counters: qform was
// grid-starved at 27% occupancy, 1.7 TB/s, VALUBusy 11%).
//   kind -> (group k, chunk c): group rows a..a+3 (a=4k), columns
//   [c0, c1) = [a+16c, min(a+16c+16, 100)). 91 kinds x 13 tiles = 1183
//   blocks (~4.6/CU; LDS 32KB and VGPR 64 allow ~full residency).
//   512 threads = 8 waves = (2 row-halves rh) x (2 d-parities dph)
//                         x (2 image-halves imgh); acc[2][4]=32 VGPR.
//   Chunk 0 contains the group triangle -> R4 peel (d0 = r0+dph, diag 0.5);
//   chunks >=1 are uniform full-weight (c0 parity == a parity since CH even).
//   cov non-temporal (single-touch; keeps 5 MB xbuf L2-resident).
//   Cross-wave sum via 32 KB LDS -> per-kind qpart store (idempotent).
// ---------------------------------------------------------------------------
__global__ __launch_bounds__(512, 4) void qform_kernel(
    const half4* __restrict__ xbuf, const float* __restrict__ cov,
    float* __restrict__ qpart)
{
    __shared__ f32x4 lred[8 * 4 * 64];   // [wave][img-slot][lane] = 32 KB

    const int tile = blockIdx.x % NT4;
    const int kind = blockIdx.x / NT4;

    // decode kind -> (k, chunk) ; wave-uniform scalar loop (<=25 iters)
    int k = 0, c = kind;
    for (int kk = 0; kk < NG; ++kk) {
        const int nc = (CC - 4 * kk + CH - 1) / CH;
        if (c < nc) { k = kk; break; }
        c -= nc;
    }
    const int a  = 4 * k;
    const int c0 = a + c * CH;
    const int c1 = min(c0 + CH, CC);

    const int w    = threadIdx.x >> 6;   // wave id 0..7
    const int dph  = w & 1;              // d parity phase
    const int rh   = (w >> 1) & 1;       // row half: rows a+2rh, a+2rh+1
    const int imgh = w >> 2;             // image half (0: n=0..3, 1: n=4..7)
    const int lane = threadIdx.x & 63;
    const int qraw = tile * 64 + lane;
    const bool valid = qraw < NPIX4;
    const int quad = valid ? qraw : (NPIX4 - 1);   // clamp, no early return

    const int r0 = a + 2 * rh;
    const int r1 = r0 + 1;

    const f32x4* c4  = (const f32x4*)cov;
    const half8* xb8 = (const half8*)xbuf;

    f32x4 acc[2][4];                     // [row in half][img]
#pragma unroll
    for (int i = 0; i < 2; ++i)
#pragma unroll
        for (int j = 0; j < 4; ++j) acc[i][j] = (f32x4){0.f, 0.f, 0.f, 0.f};

    int lo, hi = c1;
    if (c == 0) {
        // chunk 0: peel d0 = r0 + dph (diagonal handling), then full cols
        const int d0 = r0 + dph;
        {
            const half8* xp = xb8 + ((size_t)d0 * NPIX4 + quad) * 4 + imgh * 2;
            const half8 hA = xp[0];
            const half8 hB = xp[1];
            f32x4 xv[4];
            xv[0] = cvtlo(hA); xv[1] = cvthi(hA);
            xv[2] = cvtlo(hB); xv[3] = cvthi(hB);
            f32x4 cv0 = __builtin_nontemporal_load(&c4[((size_t)r0 * CC + d0) * NPIX4 + quad]);
            if (dph == 0) {
                cv0 *= 0.5f;             // d0 == r0: diagonal of r0; r1 untouched
#pragma unroll
                for (int j = 0; j < 4; ++j) acc[0][j] = fmav(xv[j], cv0, acc[0][j]);
            } else {
                // d0 == r1: r0 full, r1 diagonal
#pragma unroll
                for (int j = 0; j < 4; ++j) acc[0][j] = fmav(xv[j], cv0, acc[0][j]);
                f32x4 cv1 = __builtin_nontemporal_load(&c4[((size_t)r1 * CC + d0) * NPIX4 + quad]);
                cv1 *= 0.5f;
#pragma unroll
                for (int j = 0; j < 4; ++j) acc[1][j] = fmav(xv[j], cv1, acc[1][j]);
            }
        }
        lo = r0 + dph + 2;
    } else {
        lo = c0 + dph;                   // c0 parity == a parity (CH even)
    }

    // ---- main loop, unrolled x2 (8 loads in flight), both rows full ----
    int d = lo;
    for (; d + 2 < hi; d += 4) {
        const half8* xp0 = xb8 + ((size_t)d * NPIX4 + quad) * 4 + imgh * 2;
        const half8* xp1 = xb8 + ((size_t)(d + 2) * NPIX4 + quad) * 4 + imgh * 2;
        const half8 a0 = xp0[0];
        const half8 b0 = xp0[1];
        const half8 a1 = xp1[0];
        const half8 b1 = xp1[1];
        const size_t cb0 = ((size_t)r0 * CC + d) * NPIX4 + quad;
        const size_t cb1 = ((size_t)r1 * CC + d) * NPIX4 + quad;
        const f32x4 c00 = __builtin_nontemporal_load(&c4[cb0]);
        const f32x4 c10 = __builtin_nontemporal_load(&c4[cb1]);
        const f32x4 c01 = __builtin_nontemporal_load(&c4[cb0 + 2 * NPIX4]);
        const f32x4 c11 = __builtin_nontemporal_load(&c4[cb1 + 2 * NPIX4]);

        {
            f32x4 xv[4];
            xv[0] = cvtlo(a0); xv[1] = cvthi(a0);
            xv[2] = cvtlo(b0); xv[3] = cvthi(b0);
#pragma unroll
            for (int j = 0; j < 4; ++j) acc[0][j] = fmav(xv[j], c00, acc[0][j]);
#pragma unroll
            for (int j = 0; j < 4; ++j) acc[1][j] = fmav(xv[j], c10, acc[1][j]);
        }
        {
            f32x4 xv[4];
            xv[0] = cvtlo(a1); xv[1] = cvthi(a1);
            xv[2] = cvtlo(b1); xv[3] = cvthi(b1);
#pragma unroll
            for (int j = 0; j < 4; ++j) acc[0][j] = fmav(xv[j], c01, acc[0][j]);
#pragma unroll
            for (int j = 0; j < 4; ++j) acc[1][j] = fmav(xv[j], c11, acc[1][j]);
        }
    }
    if (d < hi) {                        // tail column
        const half8* xp = xb8 + ((size_t)d * NPIX4 + quad) * 4 + imgh * 2;
        const half8 hA = xp[0];
        const half8 hB = xp[1];
        const f32x4 cv0 = __builtin_nontemporal_load(&c4[((size_t)r0 * CC + d) * NPIX4 + quad]);
        const f32x4 cv1 = __builtin_nontemporal_load(&c4[((size_t)r1 * CC + d) * NPIX4 + quad]);
        f32x4 xv[4];
        xv[0] = cvtlo(hA); xv[1] = cvthi(hA);
        xv[2] = cvtlo(hB); xv[3] = cvthi(hB);
#pragma unroll
        for (int j = 0; j < 4; ++j) acc[0][j] = fmav(xv[j], cv0, acc[0][j]);
#pragma unroll
        for (int j = 0; j < 4; ++j) acc[1][j] = fmav(xv[j], cv1, acc[1][j]);
    }

    // ---- fold: part[j] = 2*(x_r0[j]*acc0[j] + x_r1[j]*acc1[j]); LDS dump ----
    {
        const half8* x0p = xb8 + ((size_t)r0 * NPIX4 + quad) * 4 + imgh * 2;
        const half8* x1p = xb8 + ((size_t)r1 * NPIX4 + quad) * 4 + imgh * 2;
        const half8 xa0 = x0p[0], xb0 = x0p[1];
        const half8 xa1 = x1p[0], xb1 = x1p[1];
        f32x4 part[4];
        part[0] = cvtlo(xa0) * acc[0][0];
        part[1] = cvthi(xa0) * acc[0][1];
        part[2] = cvtlo(xb0) * acc[0][2];
        part[3] = cvthi(xb0) * acc[0][3];
        part[0] = fmav(cvtlo(xa1), acc[1][0], part[0]);
        part[1] = fmav(cvthi(xa1), acc[1][1], part[1]);
        part[2] = fmav(cvtlo(xb1), acc[1][2], part[2]);
        part[3] = fmav(cvthi(xb1), acc[1][3], part[3]);
#pragma unroll
        for (int j = 0; j < 4; ++j) {
            part[j] = part[j] + part[j];             // x2 (symmetry)
            lred[(w * 4 + j) * 64 + lane] = part[j];
        }
    }
    __syncthreads();

    // ---- final: wave w stores image w's block-partial to qpart[kind] ----
    {
        const int im = w;                // 0..7
        const int sh = (im >> 2) * 4;    // source imgh base wave
        const int sl = im & 3;           // slot within image half
        f32x4 s = (f32x4){0.f, 0.f, 0.f, 0.f};
#pragma unroll
        for (int sw = 0; sw < 4; ++sw) { // (rh, dph) combos
            s = s + lred[((sh + sw) * 4 + sl) * 64 + lane];
        }
        if (valid) {
            ((f32x4*)qpart)[((size_t)kind * NN + im) * NPIX4 + qraw] = s;
        }
    }
}

// ---------------------------------------------------------------------------
// Kernel 2: reduce 91 kind-partials, split 7-way over kind-groups (13 kinds
// each) for memory parallelism; atomicAdd into prep-zeroed smap.
// ---------------------------------------------------------------------------
__global__ __launch_bounds__(256) void reduce_kernel(
    const float* __restrict__ qpart, float* __restrict__ smap)
{
    const int idx = blockIdx.x * 256 + threadIdx.x;   // over NN*NPIX4
    const int kg  = blockIdx.y;                       // kind group 0..6
    if (idx >= NN * NPIX4) return;
    const int p4 = idx % NPIX4;
    const int n  = idx / NPIX4;

    const f32x4* qp = (const f32x4*)qpart;
    f32x4 acc = (f32x4){0.f, 0.f, 0.f, 0.f};
#pragma unroll
    for (int kk = kg * 13; kk < kg * 13 + 13; ++kk) {
        acc = acc + qp[((size_t)kk * NN + n) * NPIX4 + p4];
    }
    float* dst = smap + (size_t)n * HW + (size_t)p4 * 4;
    atomicAdd(dst + 0, acc.x);
    atomicAdd(dst + 1, acc.y);
    atomicAdd(dst + 2, acc.z);
    atomicAdd(dst + 3, acc.w);
}

// ---------------------------------------------------------------------------
// Kernel 3: sqrt + bilinear x4 upsample (half-pixel, edge clamp) + normalize
// ---------------------------------------------------------------------------
__global__ __launch_bounds__(256) void upsample_kernel(
    const float* __restrict__ smap,
    const float* __restrict__ minp, const float* __restrict__ maxp,
    float* __restrict__ out)
{
    const int idx = blockIdx.x * 256 + threadIdx.x;
    const int total = NN * OH * OW;
    if (idx >= total) return;

    const int ox = idx % OW;
    const int oy = (idx / OW) % OH;
    const int n  = idx / (OW * OH);

    const float fy = oy * 0.25f - 0.375f;
    const float fx = ox * 0.25f - 0.375f;

    int y0 = (int)floorf(fy);
    int x0 = (int)floorf(fx);
    const float wy = fy - (float)y0;
    const float wx = fx - (float)x0;
    int y1 = min(y0 + 1, HH - 1); y0 = max(y0, 0);
    int x1 = min(x0 + 1, WW - 1); x0 = max(x0, 0);

    const float* s = smap + (size_t)n * HW;
    const float v00 = sqrtf(fmaxf(s[y0 * WW + x0], 0.f));
    const float v01 = sqrtf(fmaxf(s[y0 * WW + x1], 0.f));
    const float v10 = sqrtf(fmaxf(s[y1 * WW + x0], 0.f));
    const float v11 = sqrtf(fmaxf(s[y1 * WW + x1], 0.f));

    const float v = (1.0f - wy) * ((1.0f - wx) * v00 + wx * v01)
                  +          wy * ((1.0f - wx) * v10 + wx * v11);

    const float mn = *minp;
    const float mx = *maxp;
    out[idx] = (v - mn) / (mx - mn);
}

// ---------------------------------------------------------------------------
extern "C" void kernel_launch(void* const* d_in, const int* in_sizes, int n_in,
                              void* d_out, int out_size, void* d_ws, size_t ws_size,
                              hipStream_t stream)
{
    const float* fmaps = (const float*)d_in[0];
    const int*   sel   = (const int*)  d_in[1];
    const float* mean  = (const float*)d_in[2];
    const float* cov   = (const float*)d_in[3];
    const float* minp  = (const float*)d_in[4];
    const float* maxp  = (const float*)d_in[5];
    float* out = (float*)d_out;

    half4* xbuf  = (half4*)d_ws;                                      // 5.02 MB
    float* qpart = (float*)((char*)d_ws + (size_t)CC*NPIX4*NN*8);     // NKIND*NN*HW f32 = 9.13 MB
    float* smap  = qpart + (size_t)NKIND * NN * HW;                   // NN*HW f32 = 0.1 MB

    {
        const int total = CC * NPIX4;
        prep_x_kernel<<<(total + 255) / 256, 256, 0, stream>>>(fmaps, sel, mean, xbuf, smap);
    }
    qform_kernel<<<NKIND * NT4, 512, 0, stream>>>(xbuf, cov, qpart);
    {
        dim3 grid((NN * NPIX4 + 255) / 256, KG);
        reduce_kernel<<<grid, 256, 0, stream>>>(qpart, smap);
    }
    {
        const int total = NN * OH * OW;
        upsample_kernel<<<(total + 255) / 256, 256, 0, stream>>>(smap, minp, maxp, out);
    }
}